// Round 8
// baseline (120.491 us; speedup 1.0000x reference)
//
#include <hip/hip_runtime.h>
#include <math.h>

// Problem constants
#define Bdim 64
#define Ldim 1024
#define Hdim 768
#define Sdim 32
#define NHdim 8
#define HDdim 96
#define SEP_ID 102

typedef unsigned short ushort_t;
typedef __attribute__((ext_vector_type(8))) short bf16x8;
typedef __attribute__((ext_vector_type(4))) float f32x4;

// fp32 -> bf16 round-to-nearest-even
__device__ __forceinline__ ushort_t f2b(float f) {
    unsigned u = __builtin_bit_cast(unsigned, f);
    u += 0x7fffu + ((u >> 16) & 1u);
    return (ushort_t)(u >> 16);
}
__device__ __forceinline__ float b2f(ushort_t v) {
    unsigned u = ((unsigned)v) << 16;
    return __builtin_bit_cast(float, u);
}

// ---------------------------------------------------------------------------
// Kernel 1: fused prep + pool.
// Blocks [0,2048): per-(b,s) segment-mean pooling with in-block SEP scan.
// Blocks [2048,6656): weight fp32->bf16 conversion (192 float4/block).
// ---------------------------------------------------------------------------
__global__ __launch_bounds__(192) void prep_pool_kernel(const float* __restrict__ seq,
                                                        const int* __restrict__ ids,
                                                        const int* __restrict__ amask,
                                                        const float* __restrict__ w0,
                                                        const float* __restrict__ w1,
                                                        const float* __restrict__ w2,
                                                        const float* __restrict__ w3,
                                                        ushort_t* __restrict__ wdst,
                                                        ushort_t* __restrict__ reps) {
    int blk = blockIdx.x;
    int t = threadIdx.x;
    if (blk >= 2048) {
        // ---- weight conversion path ----
        int idx = (blk - 2048) * 192 + t;  // float4 units, < 884736
        const float* src; int off;
        if (idx < 147456)      { src = w0; off = idx; }
        else if (idx < 589824) { src = w1; off = idx - 147456; }
        else if (idx < 737280) { src = w2; off = idx - 589824; }
        else                   { src = w3; off = idx - 737280; }
        float4 v = ((const float4*)src)[off];
        ushort4 ov; ov.x = f2b(v.x); ov.y = f2b(v.y); ov.z = f2b(v.z); ov.w = f2b(v.w);
        ((ushort4*)wdst)[idx] = ov;
        return;
    }
    // ---- pooling path ----
    int b = blk >> 5, s = blk & 31;
    __shared__ unsigned long long masks[18];
    const int* idrow = ids + (size_t)b * Ldim;
    int wv = t >> 6, ln = t & 63;
#pragma unroll
    for (int r = 0; r < 6; ++r) {
        int p = r * 192 + t;
        bool is = (p < Ldim) && (idrow[p] == SEP_ID);
        unsigned long long m = __ballot(is);
        if (ln == 0) masks[r * 3 + wv] = m;
    }
    __syncthreads();
    // find (s-1)-th and s-th SEP position (defaults L-1), uniform per thread
    int start, end;
    {
        int need0 = s - 1, need1 = s;
        int p0 = Ldim - 1, p1 = Ldim - 1;
        int cnt = 0;
#pragma unroll
        for (int i = 0; i < 18; ++i) {
            unsigned long long mk = masks[i];
            int pc = __popcll(mk);
            int base = (i / 3) * 192 + (i % 3) * 64;
            if (need0 >= cnt && need0 < cnt + pc) {
                unsigned long long mm = mk;
                for (int j = cnt; j < need0; ++j) mm &= mm - 1;
                p0 = base + __ffsll(mm) - 1;
            }
            if (need1 >= cnt && need1 < cnt + pc) {
                unsigned long long mm = mk;
                for (int j = cnt; j < need1; ++j) mm &= mm - 1;
                p1 = base + __ffsll(mm) - 1;
            }
            cnt += pc;
        }
        start = (s == 0) ? 0 : p0;
        end = p1;
    }
    const float* base = seq + (size_t)b * Ldim * Hdim;
    const int* am = amask + b * Ldim;
    float4 A0 = {0,0,0,0}, A1 = {0,0,0,0}, A2 = {0,0,0,0}, A3 = {0,0,0,0};
    float d0 = 0.f, d1 = 0.f, d2 = 0.f, d3 = 0.f;
    int l = start;
    for (; l + 3 <= end; l += 4) {
        float m0 = (float)am[l],     m1 = (float)am[l + 1];
        float m2 = (float)am[l + 2], m3 = (float)am[l + 3];
        float4 v0 = ((const float4*)(base + (size_t)l * Hdim))[t];
        float4 v1 = ((const float4*)(base + (size_t)(l + 1) * Hdim))[t];
        float4 v2 = ((const float4*)(base + (size_t)(l + 2) * Hdim))[t];
        float4 v3 = ((const float4*)(base + (size_t)(l + 3) * Hdim))[t];
        d0 += m0; d1 += m1; d2 += m2; d3 += m3;
        A0.x += m0 * v0.x; A0.y += m0 * v0.y; A0.z += m0 * v0.z; A0.w += m0 * v0.w;
        A1.x += m1 * v1.x; A1.y += m1 * v1.y; A1.z += m1 * v1.z; A1.w += m1 * v1.w;
        A2.x += m2 * v2.x; A2.y += m2 * v2.y; A2.z += m2 * v2.z; A2.w += m2 * v2.w;
        A3.x += m3 * v3.x; A3.y += m3 * v3.y; A3.z += m3 * v3.z; A3.w += m3 * v3.w;
    }
    for (; l <= end; ++l) {
        float m0 = (float)am[l];
        float4 v0 = ((const float4*)(base + (size_t)l * Hdim))[t];
        d0 += m0;
        A0.x += m0 * v0.x; A0.y += m0 * v0.y; A0.z += m0 * v0.z; A0.w += m0 * v0.w;
    }
    float denom = d0 + d1 + d2 + d3;
    float inv = 1.f / (denom + 1e-10f);
    float4 acc;
    acc.x = (A0.x + A1.x + A2.x + A3.x) * inv;
    acc.y = (A0.y + A1.y + A2.y + A3.y) * inv;
    acc.z = (A0.z + A1.z + A2.z + A3.z) * inv;
    acc.w = (A0.w + A1.w + A2.w + A3.w) * inv;
    ushort4 o;
    o.x = f2b(acc.x); o.y = f2b(acc.y); o.z = f2b(acc.z); o.w = f2b(acc.w);
    ((ushort4*)(reps + (size_t)blk * Hdim))[t] = o;
}

// ---------------------------------------------------------------------------
// Kernel 2: bf16 MFMA GEMM: C[M,N](bf16) = A[M,K](bf16) @ W[N,K](bf16)^T + b.
// BM=128, BN=64, BK=64. 4 waves; wave tile 64x32 = 4x2 MFMA frags
// (6 ds_read_b128 per 8 MFMA per K-half — 2x better FLOP/LDS-byte).
// XOR-swizzled LDS (pre-swizzled global src, swizzled ds_read), dbuf.
// ---------------------------------------------------------------------------
__global__ __launch_bounds__(256) void gemm_mfma(const ushort_t* __restrict__ A,
                                                 const ushort_t* __restrict__ W,
                                                 const float* __restrict__ bias,
                                                 ushort_t* __restrict__ Cout,
                                                 int M, int N, int K) {
    __shared__ __attribute__((aligned(16))) ushort_t Al[2][128][64];  // 32 KB
    __shared__ __attribute__((aligned(16))) ushort_t Bl[2][64][64];   // 16 KB
    int tid = threadIdx.x;
    int wid = tid >> 6, lane = tid & 63;
    int rowBase = blockIdx.x * 128, colBase = blockIdx.y * 64;
    int wm = (wid >> 1) * 64, wn = (wid & 1) * 32;

    int srow = lane >> 3;
    int sblk = (lane & 7) ^ srow;
    // A: wave covers rows [wid*32, wid*32+32); B: rows [wid*16, wid*16+16)
    const ushort_t* Abase = A + (size_t)(rowBase + wid * 32 + srow) * K + sblk * 8;
    const ushort_t* Wbase = W + (size_t)(colBase + wid * 16 + srow) * K + sblk * 8;

    f32x4 acc[4][2] = {};

#define STAGE(bufi, kofs)                                                                     \
    do {                                                                                      \
        const ushort_t* ag = Abase + (kofs);                                                  \
        const ushort_t* wg = Wbase + (kofs);                                                  \
        __builtin_amdgcn_global_load_lds(ag,          &Al[bufi][wid * 32][0],      16, 0, 0); \
        __builtin_amdgcn_global_load_lds(ag + 8 * K,  &Al[bufi][wid * 32 + 8][0],  16, 0, 0); \
        __builtin_amdgcn_global_load_lds(ag + 16 * K, &Al[bufi][wid * 32 + 16][0], 16, 0, 0); \
        __builtin_amdgcn_global_load_lds(ag + 24 * K, &Al[bufi][wid * 32 + 24][0], 16, 0, 0); \
        __builtin_amdgcn_global_load_lds(wg,          &Bl[bufi][wid * 16][0],      16, 0, 0); \
        __builtin_amdgcn_global_load_lds(wg + 8 * K,  &Bl[bufi][wid * 16 + 8][0],  16, 0, 0); \
    } while (0)

    STAGE(0, 0);
    __syncthreads();
    int nk = K >> 6;
    int lr = lane & 15;
    int lxor = lane & 7;
    for (int t = 0; t < nk; ++t) {
        if (t + 1 < nk) STAGE((t + 1) & 1, (t + 1) * 64);
        int cb = t & 1;
#pragma unroll
        for (int ks = 0; ks < 2; ++ks) {
            int pblk = ((ks * 4 + (lane >> 4)) ^ lxor) * 8;
            bf16x8 af[4], wf[2];
#pragma unroll
            for (int i = 0; i < 4; ++i)
                af[i] = *(const bf16x8*)&Al[cb][wm + i * 16 + lr][pblk];
#pragma unroll
            for (int j = 0; j < 2; ++j)
                wf[j] = *(const bf16x8*)&Bl[cb][wn + j * 16 + lr][pblk];
#pragma unroll
            for (int i = 0; i < 4; ++i)
#pragma unroll
                for (int j = 0; j < 2; ++j)
                    acc[i][j] = __builtin_amdgcn_mfma_f32_16x16x32_bf16(af[i], wf[j], acc[i][j], 0, 0, 0);
        }
        __syncthreads();
    }
#undef STAGE

    int lrow = (lane >> 4) * 4, lcol = lane & 15;
#pragma unroll
    for (int ni = 0; ni < 2; ++ni) {
        int c = colBase + wn + ni * 16 + lcol;
        float bv = bias[c];
#pragma unroll
        for (int mi = 0; mi < 4; ++mi) {
            int rb = rowBase + wm + mi * 16 + lrow;
#pragma unroll
            for (int j = 0; j < 4; ++j)
                Cout[(size_t)(rb + j) * N + c] = f2b(acc[mi][ni][j] + bv);
        }
    }
}

// ---------------------------------------------------------------------------
// Kernel 3: row LayerNorm + exact GELU, bf16 in -> bf16 out. 192 thr/row.
// ---------------------------------------------------------------------------
__global__ __launch_bounds__(192) void ln_gelu(const ushort_t* __restrict__ X,
                                               const float* __restrict__ g,
                                               const float* __restrict__ bt,
                                               ushort_t* __restrict__ Y) {
    int row = blockIdx.x;
    int t = threadIdx.x;
    ushort4 v = ((const ushort4*)(X + (size_t)row * Hdim))[t];
    float vals[4] = { b2f(v.x), b2f(v.y), b2f(v.z), b2f(v.w) };
    float s = vals[0] + vals[1] + vals[2] + vals[3];
    float s2 = vals[0]*vals[0] + vals[1]*vals[1] + vals[2]*vals[2] + vals[3]*vals[3];
#pragma unroll
    for (int off = 32; off; off >>= 1) { s += __shfl_down(s, off); s2 += __shfl_down(s2, off); }
    __shared__ float red[6];
    int wid = t >> 6;
    if ((t & 63) == 0) { red[wid * 2] = s; red[wid * 2 + 1] = s2; }
    __syncthreads();
    s  = red[0] + red[2] + red[4];
    s2 = red[1] + red[3] + red[5];
    float mean = s / Hdim;
    float var  = s2 / Hdim - mean * mean;
    float rstd = rsqrtf(var + 1e-5f);
    float4 gv = ((const float4*)g)[t];
    float4 bv = ((const float4*)bt)[t];
    float gg[4] = { gv.x, gv.y, gv.z, gv.w };
    float bb[4] = { bv.x, bv.y, bv.z, bv.w };
    ushort4 o;
    ushort_t* op = (ushort_t*)&o;
#pragma unroll
    for (int i = 0; i < 4; ++i) {
        float xn = (vals[i] - mean) * rstd * gg[i] + bb[i];
        float ge = 0.5f * xn * (1.f + erff(xn * 0.70710678118654752f));
        op[i] = f2b(ge);
    }
    ((ushort4*)(Y + (size_t)row * Hdim))[t] = o;
}

// ---------------------------------------------------------------------------
// Kernel 4: attention per (b,h). bf16 qkv in, bf16 o out.
// ---------------------------------------------------------------------------
__global__ __launch_bounds__(256) void attn_kernel(const ushort_t* __restrict__ qkv,
                                                   ushort_t* __restrict__ o) {
    int bh = blockIdx.x;
    int b = bh >> 3, h = bh & 7;
    __shared__ float qs[Sdim][100], ks_[Sdim][100], vs[Sdim][100];
    __shared__ float sc[Sdim][33];
    int tid = threadIdx.x;
    for (int idx = tid; idx < 2304; idx += 256) {
        int m = idx / 768;
        int w = idx - m * 768;
        int s = w / 24, d4 = (w - s * 24) * 4;
        ushort4 v = *(const ushort4*)(qkv + (size_t)(b * Sdim + s) * (3 * Hdim) + m * Hdim + h * HDdim + d4);
        float* dst = (m == 0 ? &qs[s][d4] : (m == 1 ? &ks_[s][d4] : &vs[s][d4]));
        dst[0] = b2f(v.x); dst[1] = b2f(v.y); dst[2] = b2f(v.z); dst[3] = b2f(v.w);
    }
    __syncthreads();
    int ti = tid >> 4, tj = tid & 15;
    float a00 = 0.f, a01 = 0.f, a10 = 0.f, a11 = 0.f;
#pragma unroll 6
    for (int d = 0; d < HDdim; d += 4) {
        float4 q0 = *(const float4*)&qs[ti][d];
        float4 q1 = *(const float4*)&qs[ti + 16][d];
        float4 k0 = *(const float4*)&ks_[tj][d];
        float4 k1 = *(const float4*)&ks_[tj + 16][d];
        a00 += q0.x*k0.x + q0.y*k0.y + q0.z*k0.z + q0.w*k0.w;
        a01 += q0.x*k1.x + q0.y*k1.y + q0.z*k1.z + q0.w*k1.w;
        a10 += q1.x*k0.x + q1.y*k0.y + q1.z*k0.z + q1.w*k0.w;
        a11 += q1.x*k1.x + q1.y*k1.y + q1.z*k1.z + q1.w*k1.w;
    }
    const float sscale = 0.102062072615966f;  // 1/sqrt(96)
    sc[ti][tj]           = a00 * sscale;
    sc[ti][tj + 16]      = a01 * sscale;
    sc[ti + 16][tj]      = a10 * sscale;
    sc[ti + 16][tj + 16] = a11 * sscale;
    __syncthreads();
    int row = tid >> 3, jg = tid & 7;
    float v0 = sc[row][jg], v1 = sc[row][jg + 8], v2 = sc[row][jg + 16], v3 = sc[row][jg + 24];
    float mx = fmaxf(fmaxf(v0, v1), fmaxf(v2, v3));
#pragma unroll
    for (int m = 1; m <= 4; m <<= 1) mx = fmaxf(mx, __shfl_xor(mx, m));
    v0 = expf(v0 - mx); v1 = expf(v1 - mx); v2 = expf(v2 - mx); v3 = expf(v3 - mx);
    float sum = v0 + v1 + v2 + v3;
#pragma unroll
    for (int m = 1; m <= 4; m <<= 1) sum += __shfl_xor(sum, m);
    float inv = 1.f / sum;
    sc[row][jg] = v0 * inv; sc[row][jg + 8] = v1 * inv;
    sc[row][jg + 16] = v2 * inv; sc[row][jg + 24] = v3 * inv;
    __syncthreads();
    for (int idx = tid; idx < 768; idx += 256) {
        int ii = idx / 24, d4 = (idx - ii * 24) * 4;
        float o0 = 0.f, o1 = 0.f, o2 = 0.f, o3 = 0.f;
#pragma unroll 8
        for (int j = 0; j < Sdim; ++j) {
            float p = sc[ii][j];
            float4 vv = *(const float4*)&vs[j][d4];
            o0 += p * vv.x; o1 += p * vv.y; o2 += p * vv.z; o3 += p * vv.w;
        }
        ushort4 ov; ov.x = f2b(o0); ov.y = f2b(o1); ov.z = f2b(o2); ov.w = f2b(o3);
        *(ushort4*)(o + (size_t)(b * Sdim + ii) * Hdim + h * HDdim + d4) = ov;
    }
}

// ---------------------------------------------------------------------------
// Kernel 5: fused cls head — LN + GELU + logits dot. One 192-thr block/row.
// ---------------------------------------------------------------------------
__global__ __launch_bounds__(192) void cls_head_kernel(const ushort_t* __restrict__ X,
                                                       const float* __restrict__ g,
                                                       const float* __restrict__ bt,
                                                       const float* __restrict__ W2,
                                                       const float* __restrict__ b2,
                                                       float* __restrict__ out) {
    int row = blockIdx.x;
    int t = threadIdx.x;
    ushort4 v = ((const ushort4*)(X + (size_t)row * Hdim))[t];
    float vals[4] = { b2f(v.x), b2f(v.y), b2f(v.z), b2f(v.w) };
    float s = vals[0] + vals[1] + vals[2] + vals[3];
    float s2 = vals[0]*vals[0] + vals[1]*vals[1] + vals[2]*vals[2] + vals[3]*vals[3];
#pragma unroll
    for (int off = 32; off; off >>= 1) { s += __shfl_down(s, off); s2 += __shfl_down(s2, off); }
    __shared__ float red1[6], red2[6];
    int wid = t >> 6;
    if ((t & 63) == 0) { red1[wid * 2] = s; red1[wid * 2 + 1] = s2; }
    __syncthreads();
    s  = red1[0] + red1[2] + red1[4];
    s2 = red1[1] + red1[3] + red1[5];
    float mean = s / Hdim;
    float var  = s2 / Hdim - mean * mean;
    float rstd = rsqrtf(var + 1e-5f);
    float4 gv = ((const float4*)g)[t];
    float4 bv = ((const float4*)bt)[t];
    float4 w0 = ((const float4*)W2)[t];
    float4 w1 = ((const float4*)(W2 + Hdim))[t];
    float gg[4] = { gv.x, gv.y, gv.z, gv.w };
    float bb[4] = { bv.x, bv.y, bv.z, bv.w };
    float ww0[4] = { w0.x, w0.y, w0.z, w0.w };
    float ww1[4] = { w1.x, w1.y, w1.z, w1.w };
    float a0 = 0.f, a1 = 0.f;
#pragma unroll
    for (int i = 0; i < 4; ++i) {
        float xn = (vals[i] - mean) * rstd * gg[i] + bb[i];
        float ge = 0.5f * xn * (1.f + erff(xn * 0.70710678118654752f));
        a0 += ge * ww0[i];
        a1 += ge * ww1[i];
    }
#pragma unroll
    for (int off = 32; off; off >>= 1) { a0 += __shfl_down(a0, off); a1 += __shfl_down(a1, off); }
    if ((t & 63) == 0) { red2[wid * 2] = a0; red2[wid * 2 + 1] = a1; }
    __syncthreads();
    if (t == 0) {
        out[row * 2 + 0] = red2[0] + red2[2] + red2[4] + b2[0];
        out[row * 2 + 1] = red2[1] + red2[3] + red2[5] + b2[1];
    }
}

// ---------------------------------------------------------------------------
// Kernel 6: masked NLL loss. Single block.
// ---------------------------------------------------------------------------
__global__ __launch_bounds__(256) void loss_kernel(const float* __restrict__ logits,
                                                   const int* __restrict__ labels,
                                                   float* __restrict__ out) {
    int t = threadIdx.x;
    float sum = 0.f, cnt = 0.f;
    for (int i = t; i < Bdim * Sdim; i += 256) {
        int lab = labels[i];
        if (lab != -100) {
            float l0 = logits[i * 2], l1 = logits[i * 2 + 1];
            float mx = fmaxf(l0, l1);
            float lse = mx + logf(expf(l0 - mx) + expf(l1 - mx));
            sum += lse - (lab ? l1 : l0);
            cnt += 1.f;
        }
    }
#pragma unroll
    for (int off = 32; off; off >>= 1) { sum += __shfl_down(sum, off); cnt += __shfl_down(cnt, off); }
    __shared__ float red[8];
    int wid = t >> 6;
    if ((t & 63) == 0) { red[wid * 2] = sum; red[wid * 2 + 1] = cnt; }
    __syncthreads();
    if (t == 0) {
        float ts = red[0] + red[2] + red[4] + red[6];
        float tc = red[1] + red[3] + red[5] + red[7];
        out[0] = ts / fmaxf(tc, 1.f);
    }
}

// ---------------------------------------------------------------------------
extern "C" void kernel_launch(void* const* d_in, const int* in_sizes, int n_in,
                              void* d_out, int out_size, void* d_ws, size_t ws_size,
                              hipStream_t stream) {
    const int*   input_ids  = (const int*)d_in[0];
    const int*   amask      = (const int*)d_in[1];
    const int*   labels     = (const int*)d_in[2];
    const float* seq        = (const float*)d_in[3];
    const float* enc_W      = (const float*)d_in[4];
    const float* enc_b      = (const float*)d_in[5];
    const float* enc_ln_g   = (const float*)d_in[6];
    const float* enc_ln_b   = (const float*)d_in[7];
    const float* in_proj_W  = (const float*)d_in[8];
    const float* in_proj_b  = (const float*)d_in[9];
    const float* out_proj_W = (const float*)d_in[10];
    const float* out_proj_b = (const float*)d_in[11];
    const float* cls_W1     = (const float*)d_in[12];
    const float* cls_b1     = (const float*)d_in[13];
    const float* cls_ln_g   = (const float*)d_in[14];
    const float* cls_ln_b   = (const float*)d_in[15];
    const float* cls_W2     = (const float*)d_in[16];
    const float* cls_b2     = (const float*)d_in[17];

    float* out = (float*)d_out;  // [0]=loss, [1..4096]=logits

    // workspace layout (bytes), all 16B-aligned
    char* ws = (char*)d_ws;
    const size_t MS = (size_t)Bdim * Sdim;  // 2048
    ushort_t* wbf     = (ushort_t*)(ws);                         // 3538944 bf16
    ushort_t* bf_a    = (ushort_t*)(ws + 7077888);               // 2048*768
    ushort_t* bf_b    = bf_a + MS * Hdim;
    ushort_t* bf_c    = bf_b + MS * Hdim;
    ushort_t* bf_d    = bf_c + MS * Hdim;
    ushort_t* bf_qkv  = bf_d + MS * Hdim;                        // 2048*2304

    ushort_t* encWb     = wbf;
    ushort_t* inprojWb  = wbf + 589824;
    ushort_t* outprojWb = wbf + 2359296;
    ushort_t* clsW1b    = wbf + 2949120;

    // 1. fused prep (wconv) + pool -> bf_a (reps)
    prep_pool_kernel<<<6656, 192, 0, stream>>>(seq, input_ids, amask,
                                               enc_W, in_proj_W, out_proj_W, cls_W1,
                                               wbf, bf_a);
    // 2. reps @ enc_W^T + b -> bf_d
    { dim3 g(16, 12); gemm_mfma<<<g, 256, 0, stream>>>(bf_a, encWb, enc_b, bf_d, (int)MS, Hdim, Hdim); }
    // 3. LN + GELU -> bf_b (x)
    ln_gelu<<<Bdim * Sdim, 192, 0, stream>>>(bf_d, enc_ln_g, enc_ln_b, bf_b);
    // 4. x @ in_proj_W^T + b -> bf_qkv
    { dim3 g(16, 36); gemm_mfma<<<g, 256, 0, stream>>>(bf_b, inprojWb, in_proj_b, bf_qkv, (int)MS, 3 * Hdim, Hdim); }
    // 5. attention -> bf_c (o)
    attn_kernel<<<Bdim * NHdim, 256, 0, stream>>>(bf_qkv, bf_c);
    // 6. o @ out_proj_W^T + b -> bf_a (attended)
    { dim3 g(16, 12); gemm_mfma<<<g, 256, 0, stream>>>(bf_c, outprojWb, out_proj_b, bf_a, (int)MS, Hdim, Hdim); }
    // 7. attended @ cls_W1^T + b1 -> bf_d
    { dim3 g(16, 12); gemm_mfma<<<g, 256, 0, stream>>>(bf_a, clsW1b, cls_b1, bf_d, (int)MS, Hdim, Hdim); }
    // 8. fused LN + GELU + logits -> out+1
    cls_head_kernel<<<Bdim * Sdim, 192, 0, stream>>>(bf_d, cls_ln_g, cls_ln_b, cls_W2, cls_b2, out + 1);
    // 9. loss -> out[0]
    loss_kernel<<<1, 256, 0, stream>>>(out + 1, labels, out);
}

// Round 9
// 116.476 us; speedup vs baseline: 1.0345x; 1.0345x over previous
//
#include <hip/hip_runtime.h>
#include <math.h>

// Problem constants
#define Bdim 64
#define Ldim 1024
#define Hdim 768
#define Sdim 32
#define NHdim 8
#define HDdim 96
#define SEP_ID 102

typedef unsigned short ushort_t;
typedef __attribute__((ext_vector_type(8))) short bf16x8;
typedef __attribute__((ext_vector_type(4))) float f32x4;

// fp32 -> bf16 round-to-nearest-even
__device__ __forceinline__ ushort_t f2b(float f) {
    unsigned u = __builtin_bit_cast(unsigned, f);
    u += 0x7fffu + ((u >> 16) & 1u);
    return (ushort_t)(u >> 16);
}
__device__ __forceinline__ float b2f(ushort_t v) {
    unsigned u = ((unsigned)v) << 16;
    return __builtin_bit_cast(float, u);
}

// ---------------------------------------------------------------------------
// Kernel 1: fused prep + pool.
// Blocks [0,2048): per-(b,s) segment-mean pooling with in-block SEP scan,
//   8-row unrolled (8 independent float4 loads in flight per lane).
// Blocks [2048,6656): weight fp32->bf16 conversion (192 float4/block).
// ---------------------------------------------------------------------------
__global__ __launch_bounds__(192) void prep_pool_kernel(const float* __restrict__ seq,
                                                        const int* __restrict__ ids,
                                                        const int* __restrict__ amask,
                                                        const float* __restrict__ w0,
                                                        const float* __restrict__ w1,
                                                        const float* __restrict__ w2,
                                                        const float* __restrict__ w3,
                                                        ushort_t* __restrict__ wdst,
                                                        ushort_t* __restrict__ reps) {
    int blk = blockIdx.x;
    int t = threadIdx.x;
    if (blk >= 2048) {
        // ---- weight conversion path ----
        int idx = (blk - 2048) * 192 + t;  // float4 units, < 884736
        const float* src; int off;
        if (idx < 147456)      { src = w0; off = idx; }
        else if (idx < 589824) { src = w1; off = idx - 147456; }
        else if (idx < 737280) { src = w2; off = idx - 589824; }
        else                   { src = w3; off = idx - 737280; }
        float4 v = ((const float4*)src)[off];
        ushort4 ov; ov.x = f2b(v.x); ov.y = f2b(v.y); ov.z = f2b(v.z); ov.w = f2b(v.w);
        ((ushort4*)wdst)[idx] = ov;
        return;
    }
    // ---- pooling path ----
    int b = blk >> 5, s = blk & 31;
    __shared__ unsigned long long masks[18];
    const int* idrow = ids + (size_t)b * Ldim;
    int wv = t >> 6, ln = t & 63;
#pragma unroll
    for (int r = 0; r < 6; ++r) {
        int p = r * 192 + t;
        bool is = (p < Ldim) && (idrow[p] == SEP_ID);
        unsigned long long m = __ballot(is);
        if (ln == 0) masks[r * 3 + wv] = m;
    }
    __syncthreads();
    // find (s-1)-th and s-th SEP position (defaults L-1), uniform per thread
    int start, end;
    {
        int need0 = s - 1, need1 = s;
        int p0 = Ldim - 1, p1 = Ldim - 1;
        int cnt = 0;
#pragma unroll
        for (int i = 0; i < 18; ++i) {
            unsigned long long mk = masks[i];
            int pc = __popcll(mk);
            int base = (i / 3) * 192 + (i % 3) * 64;
            if (need0 >= cnt && need0 < cnt + pc) {
                unsigned long long mm = mk;
                for (int j = cnt; j < need0; ++j) mm &= mm - 1;
                p0 = base + __ffsll(mm) - 1;
            }
            if (need1 >= cnt && need1 < cnt + pc) {
                unsigned long long mm = mk;
                for (int j = cnt; j < need1; ++j) mm &= mm - 1;
                p1 = base + __ffsll(mm) - 1;
            }
            cnt += pc;
        }
        start = (s == 0) ? 0 : p0;
        end = p1;
    }
    const float* base = seq + (size_t)b * Ldim * Hdim;
    const int* am = amask + b * Ldim;
    float4 A0 = {0,0,0,0}, A1 = {0,0,0,0};
    float d0 = 0.f, d1 = 0.f;
    int l = start;
    for (; l + 7 <= end; l += 8) {
        float m[8]; float4 v[8];
#pragma unroll
        for (int r = 0; r < 8; ++r) m[r] = (float)am[l + r];
#pragma unroll
        for (int r = 0; r < 8; ++r) v[r] = ((const float4*)(base + (size_t)(l + r) * Hdim))[t];
#pragma unroll
        for (int r = 0; r < 8; ++r) {
            if (r & 1) {
                d1 += m[r];
                A1.x += m[r] * v[r].x; A1.y += m[r] * v[r].y;
                A1.z += m[r] * v[r].z; A1.w += m[r] * v[r].w;
            } else {
                d0 += m[r];
                A0.x += m[r] * v[r].x; A0.y += m[r] * v[r].y;
                A0.z += m[r] * v[r].z; A0.w += m[r] * v[r].w;
            }
        }
    }
    for (; l <= end; ++l) {
        float m0 = (float)am[l];
        float4 v0 = ((const float4*)(base + (size_t)l * Hdim))[t];
        d0 += m0;
        A0.x += m0 * v0.x; A0.y += m0 * v0.y; A0.z += m0 * v0.z; A0.w += m0 * v0.w;
    }
    float denom = d0 + d1;
    float inv = 1.f / (denom + 1e-10f);
    float4 acc;
    acc.x = (A0.x + A1.x) * inv;
    acc.y = (A0.y + A1.y) * inv;
    acc.z = (A0.z + A1.z) * inv;
    acc.w = (A0.w + A1.w) * inv;
    ushort4 o;
    o.x = f2b(acc.x); o.y = f2b(acc.y); o.z = f2b(acc.z); o.w = f2b(acc.w);
    ((ushort4*)(reps + (size_t)blk * Hdim))[t] = o;
}

// ---------------------------------------------------------------------------
// Kernel 2: bf16 MFMA GEMM: C[M,N](bf16) = A[M,K](bf16) @ W[N,K](bf16)^T + b.
// 64x64 tile, BK=64, 4 waves (2x2), each wave 32x32 = 2x2 MFMA frags.
// XOR-swizzled LDS (pre-swizzled global src, swizzled ds_read), dbuf.
// (Round-7 known-best config; the 128x64 retile regressed.)
// ---------------------------------------------------------------------------
__global__ __launch_bounds__(256) void gemm_mfma(const ushort_t* __restrict__ A,
                                                 const ushort_t* __restrict__ W,
                                                 const float* __restrict__ bias,
                                                 ushort_t* __restrict__ Cout,
                                                 int M, int N, int K) {
    __shared__ __attribute__((aligned(16))) ushort_t Al[2][64][64];
    __shared__ __attribute__((aligned(16))) ushort_t Bl[2][64][64];
    int tid = threadIdx.x;
    int wid = tid >> 6, lane = tid & 63;
    int rowBase = blockIdx.x * 64, colBase = blockIdx.y * 64;
    int wm = (wid >> 1) * 32, wn = (wid & 1) * 32;

    int srow = lane >> 3;
    int sblk = (lane & 7) ^ srow;
    const ushort_t* Abase = A + (size_t)(rowBase + wid * 16 + srow) * K + sblk * 8;
    const ushort_t* Wbase = W + (size_t)(colBase + wid * 16 + srow) * K + sblk * 8;

    f32x4 acc[2][2] = {};

#define STAGE(bufi, kofs)                                                                    \
    do {                                                                                     \
        const ushort_t* ag = Abase + (kofs);                                                 \
        const ushort_t* wg = Wbase + (kofs);                                                 \
        __builtin_amdgcn_global_load_lds(ag,           &Al[bufi][wid * 16][0],     16, 0, 0); \
        __builtin_amdgcn_global_load_lds(ag + 8 * K,   &Al[bufi][wid * 16 + 8][0], 16, 0, 0); \
        __builtin_amdgcn_global_load_lds(wg,           &Bl[bufi][wid * 16][0],     16, 0, 0); \
        __builtin_amdgcn_global_load_lds(wg + 8 * K,   &Bl[bufi][wid * 16 + 8][0], 16, 0, 0); \
    } while (0)

    STAGE(0, 0);
    __syncthreads();
    int nk = K >> 6;
    int lr = lane & 15;
    int lxor = lane & 7;
    for (int t = 0; t < nk; ++t) {
        if (t + 1 < nk) STAGE((t + 1) & 1, (t + 1) * 64);
        int cb = t & 1;
#pragma unroll
        for (int ks = 0; ks < 2; ++ks) {
            int pblk = ((ks * 4 + (lane >> 4)) ^ lxor) * 8;
            bf16x8 af[2], wf[2];
            af[0] = *(const bf16x8*)&Al[cb][wm + lr][pblk];
            af[1] = *(const bf16x8*)&Al[cb][wm + 16 + lr][pblk];
            wf[0] = *(const bf16x8*)&Bl[cb][wn + lr][pblk];
            wf[1] = *(const bf16x8*)&Bl[cb][wn + 16 + lr][pblk];
#pragma unroll
            for (int i = 0; i < 2; ++i)
#pragma unroll
                for (int j = 0; j < 2; ++j)
                    acc[i][j] = __builtin_amdgcn_mfma_f32_16x16x32_bf16(af[i], wf[j], acc[i][j], 0, 0, 0);
        }
        __syncthreads();
    }
#undef STAGE

    int lrow = (lane >> 4) * 4, lcol = lane & 15;
#pragma unroll
    for (int ni = 0; ni < 2; ++ni) {
        int c = colBase + wn + ni * 16 + lcol;
        float bv = bias[c];
#pragma unroll
        for (int mi = 0; mi < 2; ++mi) {
            int rb = rowBase + wm + mi * 16 + lrow;
#pragma unroll
            for (int j = 0; j < 4; ++j)
                Cout[(size_t)(rb + j) * N + c] = f2b(acc[mi][ni][j] + bv);
        }
    }
}

// ---------------------------------------------------------------------------
// Kernel 3: row LayerNorm + exact GELU, bf16 in -> bf16 out. 192 thr/row.
// ---------------------------------------------------------------------------
__global__ __launch_bounds__(192) void ln_gelu(const ushort_t* __restrict__ X,
                                               const float* __restrict__ g,
                                               const float* __restrict__ bt,
                                               ushort_t* __restrict__ Y) {
    int row = blockIdx.x;
    int t = threadIdx.x;
    ushort4 v = ((const ushort4*)(X + (size_t)row * Hdim))[t];
    float vals[4] = { b2f(v.x), b2f(v.y), b2f(v.z), b2f(v.w) };
    float s = vals[0] + vals[1] + vals[2] + vals[3];
    float s2 = vals[0]*vals[0] + vals[1]*vals[1] + vals[2]*vals[2] + vals[3]*vals[3];
#pragma unroll
    for (int off = 32; off; off >>= 1) { s += __shfl_down(s, off); s2 += __shfl_down(s2, off); }
    __shared__ float red[6];
    int wid = t >> 6;
    if ((t & 63) == 0) { red[wid * 2] = s; red[wid * 2 + 1] = s2; }
    __syncthreads();
    s  = red[0] + red[2] + red[4];
    s2 = red[1] + red[3] + red[5];
    float mean = s / Hdim;
    float var  = s2 / Hdim - mean * mean;
    float rstd = rsqrtf(var + 1e-5f);
    float4 gv = ((const float4*)g)[t];
    float4 bv = ((const float4*)bt)[t];
    float gg[4] = { gv.x, gv.y, gv.z, gv.w };
    float bb[4] = { bv.x, bv.y, bv.z, bv.w };
    ushort4 o;
    ushort_t* op = (ushort_t*)&o;
#pragma unroll
    for (int i = 0; i < 4; ++i) {
        float xn = (vals[i] - mean) * rstd * gg[i] + bb[i];
        float ge = 0.5f * xn * (1.f + erff(xn * 0.70710678118654752f));
        op[i] = f2b(ge);
    }
    ((ushort4*)(Y + (size_t)row * Hdim))[t] = o;
}

// ---------------------------------------------------------------------------
// Kernel 4: attention per (b,h). bf16 qkv in, bf16 o out.
// ---------------------------------------------------------------------------
__global__ __launch_bounds__(256) void attn_kernel(const ushort_t* __restrict__ qkv,
                                                   ushort_t* __restrict__ o) {
    int bh = blockIdx.x;
    int b = bh >> 3, h = bh & 7;
    __shared__ float qs[Sdim][100], ks_[Sdim][100], vs[Sdim][100];
    __shared__ float sc[Sdim][33];
    int tid = threadIdx.x;
    for (int idx = tid; idx < 2304; idx += 256) {
        int m = idx / 768;
        int w = idx - m * 768;
        int s = w / 24, d4 = (w - s * 24) * 4;
        ushort4 v = *(const ushort4*)(qkv + (size_t)(b * Sdim + s) * (3 * Hdim) + m * Hdim + h * HDdim + d4);
        float* dst = (m == 0 ? &qs[s][d4] : (m == 1 ? &ks_[s][d4] : &vs[s][d4]));
        dst[0] = b2f(v.x); dst[1] = b2f(v.y); dst[2] = b2f(v.z); dst[3] = b2f(v.w);
    }
    __syncthreads();
    int ti = tid >> 4, tj = tid & 15;
    float a00 = 0.f, a01 = 0.f, a10 = 0.f, a11 = 0.f;
#pragma unroll 6
    for (int d = 0; d < HDdim; d += 4) {
        float4 q0 = *(const float4*)&qs[ti][d];
        float4 q1 = *(const float4*)&qs[ti + 16][d];
        float4 k0 = *(const float4*)&ks_[tj][d];
        float4 k1 = *(const float4*)&ks_[tj + 16][d];
        a00 += q0.x*k0.x + q0.y*k0.y + q0.z*k0.z + q0.w*k0.w;
        a01 += q0.x*k1.x + q0.y*k1.y + q0.z*k1.z + q0.w*k1.w;
        a10 += q1.x*k0.x + q1.y*k0.y + q1.z*k0.z + q1.w*k0.w;
        a11 += q1.x*k1.x + q1.y*k1.y + q1.z*k1.z + q1.w*k1.w;
    }
    const float sscale = 0.102062072615966f;  // 1/sqrt(96)
    sc[ti][tj]           = a00 * sscale;
    sc[ti][tj + 16]      = a01 * sscale;
    sc[ti + 16][tj]      = a10 * sscale;
    sc[ti + 16][tj + 16] = a11 * sscale;
    __syncthreads();
    int row = tid >> 3, jg = tid & 7;
    float v0 = sc[row][jg], v1 = sc[row][jg + 8], v2 = sc[row][jg + 16], v3 = sc[row][jg + 24];
    float mx = fmaxf(fmaxf(v0, v1), fmaxf(v2, v3));
#pragma unroll
    for (int m = 1; m <= 4; m <<= 1) mx = fmaxf(mx, __shfl_xor(mx, m));
    v0 = expf(v0 - mx); v1 = expf(v1 - mx); v2 = expf(v2 - mx); v3 = expf(v3 - mx);
    float sum = v0 + v1 + v2 + v3;
#pragma unroll
    for (int m = 1; m <= 4; m <<= 1) sum += __shfl_xor(sum, m);
    float inv = 1.f / sum;
    sc[row][jg] = v0 * inv; sc[row][jg + 8] = v1 * inv;
    sc[row][jg + 16] = v2 * inv; sc[row][jg + 24] = v3 * inv;
    __syncthreads();
    for (int idx = tid; idx < 768; idx += 256) {
        int ii = idx / 24, d4 = (idx - ii * 24) * 4;
        float o0 = 0.f, o1 = 0.f, o2 = 0.f, o3 = 0.f;
#pragma unroll 8
        for (int j = 0; j < Sdim; ++j) {
            float p = sc[ii][j];
            float4 vv = *(const float4*)&vs[j][d4];
            o0 += p * vv.x; o1 += p * vv.y; o2 += p * vv.z; o3 += p * vv.w;
        }
        ushort4 ov; ov.x = f2b(o0); ov.y = f2b(o1); ov.z = f2b(o2); ov.w = f2b(o3);
        *(ushort4*)(o + (size_t)(b * Sdim + ii) * Hdim + h * HDdim + d4) = ov;
    }
}

// ---------------------------------------------------------------------------
// Kernel 5: fused cls head — LN + GELU + logits dot. One 192-thr block/row.
// ---------------------------------------------------------------------------
__global__ __launch_bounds__(192) void cls_head_kernel(const ushort_t* __restrict__ X,
                                                       const float* __restrict__ g,
                                                       const float* __restrict__ bt,
                                                       const float* __restrict__ W2,
                                                       const float* __restrict__ b2,
                                                       float* __restrict__ out) {
    int row = blockIdx.x;
    int t = threadIdx.x;
    ushort4 v = ((const ushort4*)(X + (size_t)row * Hdim))[t];
    float vals[4] = { b2f(v.x), b2f(v.y), b2f(v.z), b2f(v.w) };
    float s = vals[0] + vals[1] + vals[2] + vals[3];
    float s2 = vals[0]*vals[0] + vals[1]*vals[1] + vals[2]*vals[2] + vals[3]*vals[3];
#pragma unroll
    for (int off = 32; off; off >>= 1) { s += __shfl_down(s, off); s2 += __shfl_down(s2, off); }
    __shared__ float red1[6], red2[6];
    int wid = t >> 6;
    if ((t & 63) == 0) { red1[wid * 2] = s; red1[wid * 2 + 1] = s2; }
    __syncthreads();
    s  = red1[0] + red1[2] + red1[4];
    s2 = red1[1] + red1[3] + red1[5];
    float mean = s / Hdim;
    float var  = s2 / Hdim - mean * mean;
    float rstd = rsqrtf(var + 1e-5f);
    float4 gv = ((const float4*)g)[t];
    float4 bv = ((const float4*)bt)[t];
    float4 w0 = ((const float4*)W2)[t];
    float4 w1 = ((const float4*)(W2 + Hdim))[t];
    float gg[4] = { gv.x, gv.y, gv.z, gv.w };
    float bb[4] = { bv.x, bv.y, bv.z, bv.w };
    float ww0[4] = { w0.x, w0.y, w0.z, w0.w };
    float ww1[4] = { w1.x, w1.y, w1.z, w1.w };
    float a0 = 0.f, a1 = 0.f;
#pragma unroll
    for (int i = 0; i < 4; ++i) {
        float xn = (vals[i] - mean) * rstd * gg[i] + bb[i];
        float ge = 0.5f * xn * (1.f + erff(xn * 0.70710678118654752f));
        a0 += ge * ww0[i];
        a1 += ge * ww1[i];
    }
#pragma unroll
    for (int off = 32; off; off >>= 1) { a0 += __shfl_down(a0, off); a1 += __shfl_down(a1, off); }
    if ((t & 63) == 0) { red2[wid * 2] = a0; red2[wid * 2 + 1] = a1; }
    __syncthreads();
    if (t == 0) {
        out[row * 2 + 0] = red2[0] + red2[2] + red2[4] + b2[0];
        out[row * 2 + 1] = red2[1] + red2[3] + red2[5] + b2[1];
    }
}

// ---------------------------------------------------------------------------
// Kernel 6: masked NLL loss. Single block.
// ---------------------------------------------------------------------------
__global__ __launch_bounds__(256) void loss_kernel(const float* __restrict__ logits,
                                                   const int* __restrict__ labels,
                                                   float* __restrict__ out) {
    int t = threadIdx.x;
    float sum = 0.f, cnt = 0.f;
    for (int i = t; i < Bdim * Sdim; i += 256) {
        int lab = labels[i];
        if (lab != -100) {
            float l0 = logits[i * 2], l1 = logits[i * 2 + 1];
            float mx = fmaxf(l0, l1);
            float lse = mx + logf(expf(l0 - mx) + expf(l1 - mx));
            sum += lse - (lab ? l1 : l0);
            cnt += 1.f;
        }
    }
#pragma unroll
    for (int off = 32; off; off >>= 1) { sum += __shfl_down(sum, off); cnt += __shfl_down(cnt, off); }
    __shared__ float red[8];
    int wid = t >> 6;
    if ((t & 63) == 0) { red[wid * 2] = sum; red[wid * 2 + 1] = cnt; }
    __syncthreads();
    if (t == 0) {
        float ts = red[0] + red[2] + red[4] + red[6];
        float tc = red[1] + red[3] + red[5] + red[7];
        out[0] = ts / fmaxf(tc, 1.f);
    }
}

// ---------------------------------------------------------------------------
extern "C" void kernel_launch(void* const* d_in, const int* in_sizes, int n_in,
                              void* d_out, int out_size, void* d_ws, size_t ws_size,
                              hipStream_t stream) {
    const int*   input_ids  = (const int*)d_in[0];
    const int*   amask      = (const int*)d_in[1];
    const int*   labels     = (const int*)d_in[2];
    const float* seq        = (const float*)d_in[3];
    const float* enc_W      = (const float*)d_in[4];
    const float* enc_b      = (const float*)d_in[5];
    const float* enc_ln_g   = (const float*)d_in[6];
    const float* enc_ln_b   = (const float*)d_in[7];
    const float* in_proj_W  = (const float*)d_in[8];
    const float* in_proj_b  = (const float*)d_in[9];
    const float* out_proj_W = (const float*)d_in[10];
    const float* out_proj_b = (const float*)d_in[11];
    const float* cls_W1     = (const float*)d_in[12];
    const float* cls_b1     = (const float*)d_in[13];
    const float* cls_ln_g   = (const float*)d_in[14];
    const float* cls_ln_b   = (const float*)d_in[15];
    const float* cls_W2     = (const float*)d_in[16];
    const float* cls_b2     = (const float*)d_in[17];

    float* out = (float*)d_out;  // [0]=loss, [1..4096]=logits

    // workspace layout (bytes), all 16B-aligned
    char* ws = (char*)d_ws;
    const size_t MS = (size_t)Bdim * Sdim;  // 2048
    ushort_t* wbf     = (ushort_t*)(ws);                         // 3538944 bf16
    ushort_t* bf_a    = (ushort_t*)(ws + 7077888);               // 2048*768
    ushort_t* bf_b    = bf_a + MS * Hdim;
    ushort_t* bf_c    = bf_b + MS * Hdim;
    ushort_t* bf_d    = bf_c + MS * Hdim;
    ushort_t* bf_qkv  = bf_d + MS * Hdim;                        // 2048*2304

    ushort_t* encWb     = wbf;
    ushort_t* inprojWb  = wbf + 589824;
    ushort_t* outprojWb = wbf + 2359296;
    ushort_t* clsW1b    = wbf + 2949120;

    // 1. fused prep (wconv) + pool -> bf_a (reps)
    prep_pool_kernel<<<6656, 192, 0, stream>>>(seq, input_ids, amask,
                                               enc_W, in_proj_W, out_proj_W, cls_W1,
                                               wbf, bf_a);
    // 2. reps @ enc_W^T + b -> bf_d
    { dim3 g(32, 12); gemm_mfma<<<g, 256, 0, stream>>>(bf_a, encWb, enc_b, bf_d, (int)MS, Hdim, Hdim); }
    // 3. LN + GELU -> bf_b (x)
    ln_gelu<<<Bdim * Sdim, 192, 0, stream>>>(bf_d, enc_ln_g, enc_ln_b, bf_b);
    // 4. x @ in_proj_W^T + b -> bf_qkv
    { dim3 g(32, 36); gemm_mfma<<<g, 256, 0, stream>>>(bf_b, inprojWb, in_proj_b, bf_qkv, (int)MS, 3 * Hdim, Hdim); }
    // 5. attention -> bf_c (o)
    attn_kernel<<<Bdim * NHdim, 256, 0, stream>>>(bf_qkv, bf_c);
    // 6. o @ out_proj_W^T + b -> bf_a (attended)
    { dim3 g(32, 12); gemm_mfma<<<g, 256, 0, stream>>>(bf_c, outprojWb, out_proj_b, bf_a, (int)MS, Hdim, Hdim); }
    // 7. attended @ cls_W1^T + b1 -> bf_d
    { dim3 g(32, 12); gemm_mfma<<<g, 256, 0, stream>>>(bf_a, clsW1b, cls_b1, bf_d, (int)MS, Hdim, Hdim); }
    // 8. fused LN + GELU + logits -> out+1
    cls_head_kernel<<<Bdim * Sdim, 192, 0, stream>>>(bf_d, cls_ln_g, cls_ln_b, cls_W2, cls_b2, out + 1);
    // 9. loss -> out[0]
    loss_kernel<<<1, 256, 0, stream>>>(out + 1, labels, out);
}